// Round 3
// baseline (853.772 us; speedup 1.0000x reference)
//
#include <hip/hip_runtime.h>
#include <math.h>

// CBAM pillar kernel for MI355X (gfx950) — round 18.
//
// R15 (static 2-trip): 61us @ VALUBusy 57.  R16 (1 trip/block): 64.7 —
// stage not amortized.  R17 (pipelined steal): 101 — 4096 waves serializing
// on one atomic line (~30cy/RMW) stalls every trip at the shfl.  Steal is
// dead; back to static.
//
// R18: raise resident capacity 4096 -> 5120 waves (5 blocks/CU) and hide
// voxel staging for free:
//  - wc1/wc2 leave LDS (8KB): Wc1 read direct from global (base+q*1024B,
//    imm offsets), Wc2^T staged into ws by pack_kernel.  LDS 40448->31872
//    => 5 blocks/CU by LDS.
//  - __launch_bounds__(256,5) forces VGPR<=102 (R16 body was 100).
//  - vbuf refill via global_load_lds issued right after phase-1 drain
//    (vbuf dead there); vmcnt(0) drain at trip end.  No register prefetch.
// Tail: 6250 groups / 5120 waves -> 22% of waves do a 2nd trip (was 53%).

#define CO 64

__device__ __forceinline__ float sgm(float x) {
  return 1.0f / (1.0f + __expf(-x));
}
template <int PAT>
__device__ __forceinline__ float qadd(float s) {
  int t = __builtin_amdgcn_update_dpp(0, __builtin_bit_cast(int, s),
                                      PAT, 0xf, 0xf, true);
  return s + __builtin_bit_cast(float, t);
}
template <int PAT>
__device__ __forceinline__ float qmaxd(float m) {
  int t = __builtin_amdgcn_update_dpp(__builtin_bit_cast(int, m),
                                      __builtin_bit_cast(int, m),
                                      PAT, 0xf, 0xf, false);
  return fmaxf(m, __builtin_bit_cast(float, t));
}
template <int PAT>
__device__ __forceinline__ float qmind(float m) {
  int t = __builtin_amdgcn_update_dpp(__builtin_bit_cast(int, m),
                                      __builtin_bit_cast(int, m),
                                      PAT, 0xf, 0xf, false);
  return fminf(m, __builtin_bit_cast(float, t));
}
// full exchange within each 4-lane quad: 0xB1=[1,0,3,2], 0x4E=[2,3,0,1]
__device__ __forceinline__ float qsum4(float s) { return qadd<0x4E>(qadd<0xB1>(s)); }
__device__ __forceinline__ float qmax4(float m) { return qmaxd<0x4E>(qmaxd<0xB1>(m)); }
__device__ __forceinline__ float qmin4(float m) { return qmind<0x4E>(qmind<0xB1>(m)); }
__device__ __forceinline__ void drain_lds() {
  __builtin_amdgcn_wave_barrier();
  __builtin_amdgcn_s_waitcnt(0xC07F);   // lgkmcnt(0)
  __builtin_amdgcn_wave_barrier();
}
__device__ __forceinline__ void drain_vm() {
  __builtin_amdgcn_wave_barrier();
  __builtin_amdgcn_s_waitcnt(0x0F70);   // vmcnt(0)
  __builtin_amdgcn_wave_barrier();
}

// per-voxel: pvox[2p+slot] = {vf[5], bits(bin), 0, 0}  (32B records)
// + stage Wc2^T (64x16) into ws so cbam reads it k-major from global/L1.
__global__ __launch_bounds__(256) void pack_kernel(
    const float* __restrict__ vf, const int* __restrict__ vcoord,
    const int* __restrict__ unq_inv, float* __restrict__ pvox, int n,
    const float* __restrict__ Wc2, float* __restrict__ wc2t) {
  int i = blockIdx.x * blockDim.x + threadIdx.x;
  if (i < 1024) wc2t[i] = Wc2[(i & 15) * 64 + (i >> 4)];  // [ch][j] <- [j][ch]
  if (i >= n) return;
  int p = unq_inv[i];
  int slot = (i > 0 && unq_inv[i - 1] == p) ? 1 : 0;
  float* dst = pvox + 8 * (size_t)(2 * p + slot);
#pragma unroll
  for (int k = 0; k < 5; ++k) dst[k] = vf[5 * i + k];
  ((int*)dst)[5] = vcoord[4 * i + 1];
}

__global__ __launch_bounds__(256, 5) void cbam_kernel(
    const float* __restrict__ pvox, const int* __restrict__ unq_cnt,
    const float* __restrict__ W1, const float* __restrict__ b1,
    const float* __restrict__ W2, const float* __restrict__ b2,
    const float* __restrict__ Wc1, const float* __restrict__ bc1,
    const float* __restrict__ wc2t, const float* __restrict__ bc2,
    const float* __restrict__ Wsp, const float* __restrict__ bsp,
    float* __restrict__ out, int U, int ngroups, int totalWaves) {
  __shared__ __align__(16) float w2b[2048];   // 32 x 64 (stride 64)
  __shared__ __align__(16) float c0b[64], b2b[64], bc2b[64], bc1b[16];
  __shared__ __align__(16) float wsmx[64];    // float2[32] window sums
  __shared__ __align__(16) float wtab[16];    // float2[8] taps, [7]={0,0}
  __shared__ __align__(16) float hbuf[4][1152];  // per-wave 32 x stride 36
  __shared__ __align__(16) float vbuf[4][256];   // per-wave voxel block (1KB)

  const int tid = threadIdx.x;

  // ---- stage weights to LDS (once per block; persistent blocks)
  for (int i = tid; i < 2048; i += 256) w2b[i] = W2[i];
  if (tid < 64) { b2b[tid] = b2[tid]; bc2b[tid] = bc2[tid]; }
  if (tid < 16) bc1b[tid] = bc1[tid];
  if (tid < 32) {
    float sm = 0.0f, sx = 0.0f;
    for (int k = 0; k < 7; ++k)
      if ((unsigned)(tid + k - 3) < 32u) { sm += Wsp[k]; sx += Wsp[7 + k]; }
    wsmx[2 * tid] = sm; wsmx[2 * tid + 1] = sx;
  }
  if (tid < 8) {
    float a = 0.0f, b = 0.0f;
    if (tid < 7) { a = Wsp[tid]; b = Wsp[7 + tid]; }
    wtab[2 * tid] = a; wtab[2 * tid + 1] = b;
  }
  __syncthreads();
  if (tid < 64) {                      // c0[ch] = b2 + relu(b1) @ W2
    float c = b2b[tid];
    for (int j = 0; j < 32; ++j) c += fmaxf(b1[j], 0.0f) * w2b[j * 64 + tid];
    c0b[tid] = c;
  }
  __syncthreads();

  const int wv = tid >> 6, lane = tid & 63;
  int grp = blockIdx.x * 4 + wv;       // static grid-stride schedule
  if (grp >= ngroups) return;          // all __syncthreads are above

  float* const hb = hbuf[wv];
  float* const vb = vbuf[wv];
  float4* const vb4 = (float4*)vb;

  // phase-1 constants (persist across trips)
  const int j32 = lane & 31, vh = lane >> 5;
  float w1r[5];
#pragma unroll
  for (int i = 0; i < 5; ++i) w1r[i] = W1[i * 32 + j32];
  const float b1r = b1[j32];

  const int q = lane & 3, pp = lane >> 2;
  const float4* pv4 = (const float4*)pvox;
  const int f4max = 4 * U - 1;         // pvox has 4U float4 entries

  // per-lane weight bases (imm offsets do the rest; L1-resident)
  const float4* const wc1g = (const float4*)Wc1 + (q << 6);   // + q*1024B
  const float4* const wc2g = (const float4*)wc2t + (q << 6);

  // ---- prologue: async-stage trip-0 voxel block straight to LDS
  {
    int idx = 64 * grp + lane;
    idx = idx < f4max ? idx : f4max;
    __builtin_amdgcn_global_load_lds(
        (const __attribute__((address_space(1))) void*)(pv4 + idx),
        (__attribute__((address_space(3))) void*)vb4, 16, 0, 0);
  }
  drain_vm();

  for (; grp < ngroups; grp += totalWaves) {
    const int P0 = grp * 16;           // 16 pillars this trip

    // ---- metadata (cnt global; bins from current vbuf) hoisted
    const int pg = P0 + pp;
    const int pc = pg < U ? pg : (U - 1);
    const int cnt = unq_cnt[pc];
    const int* vbi = (const int*)vb;
    const int b0 = vbi[(2 * pp) * 8 + 5] & 31;
    const int b1raw = vbi[(2 * pp + 1) * 8 + 5];

    // ---- phase 1: layer1 from vbuf.  lane = (j32, voxel-half vh)
    {
      const float4* vb4c = (const float4*)vb;
#pragma unroll
      for (int v = 0; v < 16; ++v) {
        const int rec = 16 * vh + v;
        float4 g1 = vb4c[2 * rec];       // uniform per half -> broadcast
        float4 g2 = vb4c[2 * rec + 1];
        float h = b1r + g1.x * w1r[0] + g1.y * w1r[1] + g1.z * w1r[2] +
                  g1.w * w1r[3] + g2.x * w1r[4];
        const int row = (v & 1) * 16 + 8 * vh + (v >> 1);
        hb[row * 36 + j32] = fmaxf(h, 0.0f);
      }
    }
    drain_lds();

    // ---- vbuf is dead now: issue next trip's fill straight to LDS.
    // Lands during phase 2; vmcnt(0) at trip end guards the reuse.
    {
      const int nxt = grp + totalWaves;
      if (nxt < ngroups) {
        int nidx = 64 * nxt + lane;
        nidx = nidx < f4max ? nidx : f4max;
        __builtin_amdgcn_global_load_lds(
            (const __attribute__((address_space(1))) void*)(pv4 + nidx),
            (__attribute__((address_space(3))) void*)vb4, 16, 0, 0);
      }
    }

    // ---- phase 2: lane = (pillar pp, ch-quad q); channels 16q..16q+15
    const bool has2 = (cnt >= 2);
    const int b1e = has2 ? (b1raw & 31) : 64;

    // layer2
    float y0[16], y1[16];
    const float4* b2b4 = (const float4*)b2b;
#pragma unroll
    for (int kb = 0; kb < 4; ++kb) {
      float4 w = b2b4[q * 4 + kb];
      y0[4 * kb] = w.x; y0[4 * kb + 1] = w.y; y0[4 * kb + 2] = w.z; y0[4 * kb + 3] = w.w;
      y1[4 * kb] = w.x; y1[4 * kb + 1] = w.y; y1[4 * kb + 2] = w.z; y1[4 * kb + 3] = w.w;
    }
    const float4* hb4 = (const float4*)hb;
    const float4* w2b4 = (const float4*)w2b;
    float4 h0c = hb4[pp * 9];
    float4 h1c = hb4[(16 + pp) * 9];
#pragma unroll
    for (int jb = 0; jb < 8; ++jb) {
      float4 h0n, h1n;
      if (jb < 7) {
        h0n = hb4[pp * 9 + jb + 1];
        h1n = hb4[(16 + pp) * 9 + jb + 1];
      }
      float h0a[4] = {h0c.x, h0c.y, h0c.z, h0c.w};
      float h1a[4] = {h1c.x, h1c.y, h1c.z, h1c.w};
#pragma unroll
      for (int jj = 0; jj < 4; ++jj) {
        const int j = 4 * jb + jj;
#pragma unroll
        for (int kb = 0; kb < 4; ++kb) {
          float4 w = w2b4[16 * j + 4 * q + kb];  // q 2-way banks: free
          y0[4 * kb]     += h0a[jj] * w.x; y0[4 * kb + 1] += h0a[jj] * w.y;
          y0[4 * kb + 2] += h0a[jj] * w.z; y0[4 * kb + 3] += h0a[jj] * w.w;
          y1[4 * kb]     += h1a[jj] * w.x; y1[4 * kb + 1] += h1a[jj] * w.y;
          y1[4 * kb + 2] += h1a[jj] * w.z; y1[4 * kb + 3] += h1a[jj] * w.w;
        }
      }
      h0c = h0n; h1c = h1n;
    }
#pragma unroll
    for (int k = 0; k < 16; ++k) y1[k] = has2 ? y1[k] : y0[k];

    // pooled stats + chMLP layer1 partials (thread-local over 16 ch)
    float ha[16] = {0}, hm[16] = {0};
    const float kf = has2 ? 30.0f : 31.0f;     // 32 - nocc
    const float inv32 = 1.0f / 32.0f;
    const float4* c04 = (const float4*)c0b;
#pragma unroll
    for (int kb = 0; kb < 4; ++kb) {
      float4 cq = c04[q * 4 + kb];
      float c0a[4] = {cq.x, cq.y, cq.z, cq.w};
#pragma unroll
      for (int i = 0; i < 4; ++i) {
        const int k = 4 * kb + i;
        const float c0v = c0a[i];
        const float sumy = y0[k] + (has2 ? y1[k] : 0.0f);
        const float avg = fmaf(c0v, kf, sumy) * inv32;
        const float mxv = fmaxf(fmaxf(y0[k], y1[k]), c0v);
#pragma unroll
        for (int jb = 0; jb < 4; ++jb) {
          float4 w = wc1g[4 * k + jb];           // global/L1, imm offsets
          ha[4 * jb]     += avg * w.x; ha[4 * jb + 1] += avg * w.y;
          ha[4 * jb + 2] += avg * w.z; ha[4 * jb + 3] += avg * w.w;
          hm[4 * jb]     += mxv * w.x; hm[4 * jb + 1] += mxv * w.y;
          hm[4 * jb + 2] += mxv * w.z; hm[4 * jb + 3] += mxv * w.w;
        }
      }
    }
    // quad-reduce partials, bias, relu, combine pools
    float g[16];
    const float4* bc14 = (const float4*)bc1b;
#pragma unroll
    for (int jb = 0; jb < 4; ++jb) {
      float4 bb = bc14[jb];
      float bba[4] = {bb.x, bb.y, bb.z, bb.w};
#pragma unroll
      for (int i = 0; i < 4; ++i) {
        const int j = 4 * jb + i;
        const float sa = qsum4(ha[j]) + bba[i];
        const float sm = qsum4(hm[j]) + bba[i];
        g[j] = fmaxf(sa, 0.0f) + fmaxf(sm, 0.0f);
      }
    }

    // chMLP layer2 -> attc; bin-column partial reductions
    float attc[16];
    float sc = 0.0f, mc = -3.0e38f;
    float sy0 = 0.0f, my0 = -3.0e38f, sy1 = 0.0f, my1 = -3.0e38f;
    const float4* bc24 = (const float4*)bc2b;
#pragma unroll
    for (int kb = 0; kb < 4; ++kb) {
      float4 cq = c04[q * 4 + kb];
      float4 bq = bc24[q * 4 + kb];
      float c0a[4] = {cq.x, cq.y, cq.z, cq.w};
      float b2a[4] = {bq.x, bq.y, bq.z, bq.w};
#pragma unroll
      for (int i = 0; i < 4; ++i) {
        const int k = 4 * kb + i;
        float pre = 2.0f * b2a[i];
#pragma unroll
        for (int jb = 0; jb < 4; ++jb) {
          float4 w = wc2g[4 * k + jb];           // global/L1, imm offsets
          pre += g[4 * jb] * w.x + g[4 * jb + 1] * w.y +
                 g[4 * jb + 2] * w.z + g[4 * jb + 3] * w.w;
        }
        const float a = sgm(pre);
        attc[k] = a;
        const float pc0 = a * c0a[i], py0 = a * y0[k], py1 = a * y1[k];
        sc += pc0;  mc = fmaxf(mc, pc0);
        sy0 += py0; my0 = fmaxf(my0, py0);
        sy1 += py1; my1 = fmaxf(my1, py1);
      }
    }
    sc = qsum4(sc);   mc = qmax4(mc);
    sy0 = qsum4(sy0); my0 = qmax4(my0);
    sy1 = qsum4(sy1); my1 = qmax4(my1);

    // analytic conv over 32 bins, 8 bins per lane, quad-combined
    const float inv64 = 1.0f / 64.0f;
    const float Mn = sc * inv64, Mx = mc;
    const float dm0 = (sy0 - sc) * inv64, dx0 = my0 - mc;
    const float dm1 = (sy1 - sc) * inv64, dx1 = my1 - mc;
    const float bspr = bsp[0];
    const float2* ws2 = (const float2*)wsmx;
    const float2* wt2 = (const float2*)wtab;
    float maxE = -3.0e38f, minE = 3.0e38f, sv0 = -3.0e38f, sv1 = -3.0e38f;
#pragma unroll
    for (int k = 0; k < 8; ++k) {
      const int b = 8 * q + k;
      float2 ws = ws2[b];
      float acc = bspr + Mn * ws.x + Mx * ws.y;
      int k0 = b0 - b + 3;  k0 = ((unsigned)k0 <= 6u) ? k0 : 7;
      int k1 = b1e - b + 3; k1 = ((unsigned)k1 <= 6u) ? k1 : 7;
      float2 w0 = wt2[k0];
      float2 w1v = wt2[k1];
      acc += dm0 * w0.x + dx0 * w0.y + dm1 * w1v.x + dx1 * w1v.y;
      const bool o0 = (b == b0), o1 = (b == b1e);
      const bool oc = o0 || o1;
      maxE = fmaxf(maxE, oc ? -3.0e38f : acc);
      minE = fminf(minE, oc ?  3.0e38f : acc);
      sv0 = o0 ? acc : sv0;
      sv1 = o1 ? acc : sv1;
    }
    maxE = qmax4(maxE); minE = qmin4(minE);
    sv0 = qmax4(sv0);   sv1 = qmax4(sv1);
    const float sig0 = sgm(sv0);
    const float sig1 = has2 ? sgm(sv1) : sig0;
    const float sE = sgm(maxE), sI = sgm(minE);

    // epilogue: final max over bins, stores
    if (pg < U) {
      float4* ov = (float4*)(out + (size_t)pg * CO + 16 * q);
#pragma unroll
      for (int kb = 0; kb < 4; ++kb) {
        float4 cq = c04[q * 4 + kb];
        float c0a[4] = {cq.x, cq.y, cq.z, cq.w};
        float rr[4];
#pragma unroll
        for (int i = 0; i < 4; ++i) {
          const int k = 4 * kb + i;
          const float c0v = c0a[i];
          const float sel = (c0v >= 0.0f) ? sE : sI;
          const float m = fmaxf(fmaxf(y0[k] * sig0, y1[k] * sig1), c0v * sel);
          rr[i] = attc[k] * m;
        }
        float4 r; r.x = rr[0]; r.y = rr[1]; r.z = rr[2]; r.w = rr[3];
        ov[kb] = r;
      }
      if (q == 0) out[(size_t)U * CO + pg] = has2 ? 1.0f : 0.0f;
    }

    // ---- next trip's vbuf fill must have landed before reuse
    drain_vm();
  }
}

extern "C" void kernel_launch(void* const* d_in, const int* in_sizes, int n_in,
                              void* d_out, int out_size, void* d_ws, size_t ws_size,
                              hipStream_t stream) {
  const float* vf      = (const float*)d_in[0];
  const int*   vcoord  = (const int*)d_in[1];
  // d_in[2] = unq_coords (unused: identity)
  const int*   unq_inv = (const int*)d_in[3];
  const int*   unq_cnt = (const int*)d_in[4];
  const float* W1  = (const float*)d_in[5];
  const float* b1  = (const float*)d_in[6];
  const float* W2  = (const float*)d_in[7];
  const float* b2  = (const float*)d_in[8];
  const float* Wc1 = (const float*)d_in[9];
  const float* bc1 = (const float*)d_in[10];
  const float* Wc2 = (const float*)d_in[11];
  const float* bc2 = (const float*)d_in[12];
  const float* Wsp = (const float*)d_in[13];
  const float* bsp = (const float*)d_in[14];

  const int N = in_sizes[3];   // voxels
  const int U = in_sizes[4];   // pillars

  float* pvox = (float*)d_ws;                  // 2U records x 32B
  float* wc2t = pvox + 16 * (size_t)U;         // Wc2^T staging (4KB)

  pack_kernel<<<(N + 255) / 256, 256, 0, stream>>>(vf, vcoord, unq_inv, pvox, N,
                                                   Wc2, wc2t);

  const int ngroups = (U + 15) / 16;      // 16 pillars per wave-trip
  int blocks = 1280;                      // 5 blocks/CU resident (LDS ~31.9KB)
  const int maxBlocks = (ngroups + 3) / 4;
  if (blocks > maxBlocks) blocks = maxBlocks;
  const int totalWaves = blocks * 4;
  cbam_kernel<<<blocks, 256, 0, stream>>>(
      pvox, unq_cnt, W1, b1, W2, b2, Wc1, bc1, wc2t, bc2, Wsp, bsp,
      (float*)d_out, U, ngroups, totalWaves);
}

// Round 4
// 500.151 us; speedup vs baseline: 1.7070x; 1.7070x over previous
//
#include <hip/hip_runtime.h>
#include <math.h>

// CBAM pillar kernel for MI355X (gfx950) — round 19.
//
// R18 post-mortem: __launch_bounds__(256,5) forced VGPR to 48 -> the whole
// phase-2 working set spilled to scratch (FETCH 3.6MB->869MB, WRITE 25MB->
// 1.6GB, 774us).  Structure (LDS 32256, global Wc1, staged Wc2^T,
// global_load_lds vbuf refill) was correct.  R19 = same structure, NO
// forced occupancy bound; manual shave: w1r/b1r reloaded per trip (frees
// ~6 persistent VGPRs across the phase-2 peak).  If VGPR lands <=96 the
// LDS diet gives 5 blocks/CU (20 waves/CU); else parity with R15.

#define CO 64

__device__ __forceinline__ float sgm(float x) {
  return 1.0f / (1.0f + __expf(-x));
}
template <int PAT>
__device__ __forceinline__ float qadd(float s) {
  int t = __builtin_amdgcn_update_dpp(0, __builtin_bit_cast(int, s),
                                      PAT, 0xf, 0xf, true);
  return s + __builtin_bit_cast(float, t);
}
template <int PAT>
__device__ __forceinline__ float qmaxd(float m) {
  int t = __builtin_amdgcn_update_dpp(__builtin_bit_cast(int, m),
                                      __builtin_bit_cast(int, m),
                                      PAT, 0xf, 0xf, false);
  return fmaxf(m, __builtin_bit_cast(float, t));
}
template <int PAT>
__device__ __forceinline__ float qmind(float m) {
  int t = __builtin_amdgcn_update_dpp(__builtin_bit_cast(int, m),
                                      __builtin_bit_cast(int, m),
                                      PAT, 0xf, 0xf, false);
  return fminf(m, __builtin_bit_cast(float, t));
}
// full exchange within each 4-lane quad: 0xB1=[1,0,3,2], 0x4E=[2,3,0,1]
__device__ __forceinline__ float qsum4(float s) { return qadd<0x4E>(qadd<0xB1>(s)); }
__device__ __forceinline__ float qmax4(float m) { return qmaxd<0x4E>(qmaxd<0xB1>(m)); }
__device__ __forceinline__ float qmin4(float m) { return qmind<0x4E>(qmind<0xB1>(m)); }
__device__ __forceinline__ void drain_lds() {
  __builtin_amdgcn_wave_barrier();
  __builtin_amdgcn_s_waitcnt(0xC07F);   // lgkmcnt(0)
  __builtin_amdgcn_wave_barrier();
}
__device__ __forceinline__ void drain_vm() {
  __builtin_amdgcn_wave_barrier();
  __builtin_amdgcn_s_waitcnt(0x0F70);   // vmcnt(0)
  __builtin_amdgcn_wave_barrier();
}

// per-voxel: pvox[2p+slot] = {vf[5], bits(bin), 0, 0}  (32B records)
// + stage Wc2^T (64x16) into ws so cbam reads it k-major from global/L1.
__global__ __launch_bounds__(256) void pack_kernel(
    const float* __restrict__ vf, const int* __restrict__ vcoord,
    const int* __restrict__ unq_inv, float* __restrict__ pvox, int n,
    const float* __restrict__ Wc2, float* __restrict__ wc2t) {
  int i = blockIdx.x * blockDim.x + threadIdx.x;
  if (i < 1024) wc2t[i] = Wc2[(i & 15) * 64 + (i >> 4)];  // [ch][j] <- [j][ch]
  if (i >= n) return;
  int p = unq_inv[i];
  int slot = (i > 0 && unq_inv[i - 1] == p) ? 1 : 0;
  float* dst = pvox + 8 * (size_t)(2 * p + slot);
#pragma unroll
  for (int k = 0; k < 5; ++k) dst[k] = vf[5 * i + k];
  ((int*)dst)[5] = vcoord[4 * i + 1];
}

__global__ __launch_bounds__(256) void cbam_kernel(
    const float* __restrict__ pvox, const int* __restrict__ unq_cnt,
    const float* __restrict__ W1, const float* __restrict__ b1,
    const float* __restrict__ W2, const float* __restrict__ b2,
    const float* __restrict__ Wc1, const float* __restrict__ bc1,
    const float* __restrict__ wc2t, const float* __restrict__ bc2,
    const float* __restrict__ Wsp, const float* __restrict__ bsp,
    float* __restrict__ out, int U, int ngroups, int totalWaves) {
  __shared__ __align__(16) float w2b[2048];   // 32 x 64 (stride 64)
  __shared__ __align__(16) float c0b[64], b2b[64], bc2b[64], bc1b[16];
  __shared__ __align__(16) float wsmx[64];    // float2[32] window sums
  __shared__ __align__(16) float wtab[16];    // float2[8] taps, [7]={0,0}
  __shared__ __align__(16) float hbuf[4][1152];  // per-wave 32 x stride 36
  __shared__ __align__(16) float vbuf[4][256];   // per-wave voxel block (1KB)

  const int tid = threadIdx.x;

  // ---- stage weights to LDS (once per block; persistent blocks)
  for (int i = tid; i < 2048; i += 256) w2b[i] = W2[i];
  if (tid < 64) { b2b[tid] = b2[tid]; bc2b[tid] = bc2[tid]; }
  if (tid < 16) bc1b[tid] = bc1[tid];
  if (tid < 32) {
    float sm = 0.0f, sx = 0.0f;
    for (int k = 0; k < 7; ++k)
      if ((unsigned)(tid + k - 3) < 32u) { sm += Wsp[k]; sx += Wsp[7 + k]; }
    wsmx[2 * tid] = sm; wsmx[2 * tid + 1] = sx;
  }
  if (tid < 8) {
    float a = 0.0f, b = 0.0f;
    if (tid < 7) { a = Wsp[tid]; b = Wsp[7 + tid]; }
    wtab[2 * tid] = a; wtab[2 * tid + 1] = b;
  }
  __syncthreads();
  if (tid < 64) {                      // c0[ch] = b2 + relu(b1) @ W2
    float c = b2b[tid];
    for (int j = 0; j < 32; ++j) c += fmaxf(b1[j], 0.0f) * w2b[j * 64 + tid];
    c0b[tid] = c;
  }
  __syncthreads();

  const int wv = tid >> 6, lane = tid & 63;
  int grp = blockIdx.x * 4 + wv;       // static grid-stride schedule
  if (grp >= ngroups) return;          // all __syncthreads are above

  float* const hb = hbuf[wv];
  float* const vb = vbuf[wv];
  float4* const vb4 = (float4*)vb;

  const int j32 = lane & 31, vh = lane >> 5;
  const int q = lane & 3, pp = lane >> 2;
  const float4* pv4 = (const float4*)pvox;
  const int f4max = 4 * U - 1;         // pvox has 4U float4 entries

  // per-lane weight bases (imm offsets do the rest; L1-resident)
  const float4* const wc1g = (const float4*)Wc1 + (q << 6);   // + q*1024B
  const float4* const wc2g = (const float4*)wc2t + (q << 6);

  // ---- prologue: async-stage trip-0 voxel block straight to LDS
  {
    int idx = 64 * grp + lane;
    idx = idx < f4max ? idx : f4max;
    __builtin_amdgcn_global_load_lds(
        (const __attribute__((address_space(1))) void*)(pv4 + idx),
        (__attribute__((address_space(3))) void*)vb4, 16, 0, 0);
  }
  drain_vm();

  for (; grp < ngroups; grp += totalWaves) {
    const int P0 = grp * 16;           // 16 pillars this trip

    // ---- metadata (cnt global; bins from current vbuf) hoisted
    const int pg = P0 + pp;
    const int pc = pg < U ? pg : (U - 1);
    const int cnt = unq_cnt[pc];
    const int* vbi = (const int*)vb;
    const int b0 = vbi[(2 * pp) * 8 + 5] & 31;
    const int b1raw = vbi[(2 * pp + 1) * 8 + 5];

    // ---- phase 1: layer1 from vbuf.  lane = (j32, voxel-half vh)
    // w1r/b1r reloaded per trip (L1-hot) to free persistent VGPRs.
    {
      float w1r[5];
#pragma unroll
      for (int i = 0; i < 5; ++i) w1r[i] = W1[i * 32 + j32];
      const float b1r = b1[j32];
      const float4* vb4c = (const float4*)vb;
#pragma unroll
      for (int v = 0; v < 16; ++v) {
        const int rec = 16 * vh + v;
        float4 g1 = vb4c[2 * rec];       // uniform per half -> broadcast
        float4 g2 = vb4c[2 * rec + 1];
        float h = b1r + g1.x * w1r[0] + g1.y * w1r[1] + g1.z * w1r[2] +
                  g1.w * w1r[3] + g2.x * w1r[4];
        const int row = (v & 1) * 16 + 8 * vh + (v >> 1);
        hb[row * 36 + j32] = fmaxf(h, 0.0f);
      }
    }
    drain_lds();

    // ---- vbuf is dead now: issue next trip's fill straight to LDS.
    // Lands during phase 2; vmcnt(0) at trip end guards the reuse.
    {
      const int nxt = grp + totalWaves;
      if (nxt < ngroups) {
        int nidx = 64 * nxt + lane;
        nidx = nidx < f4max ? nidx : f4max;
        __builtin_amdgcn_global_load_lds(
            (const __attribute__((address_space(1))) void*)(pv4 + nidx),
            (__attribute__((address_space(3))) void*)vb4, 16, 0, 0);
      }
    }

    // ---- phase 2: lane = (pillar pp, ch-quad q); channels 16q..16q+15
    const bool has2 = (cnt >= 2);
    const int b1e = has2 ? (b1raw & 31) : 64;

    // layer2
    float y0[16], y1[16];
    const float4* b2b4 = (const float4*)b2b;
#pragma unroll
    for (int kb = 0; kb < 4; ++kb) {
      float4 w = b2b4[q * 4 + kb];
      y0[4 * kb] = w.x; y0[4 * kb + 1] = w.y; y0[4 * kb + 2] = w.z; y0[4 * kb + 3] = w.w;
      y1[4 * kb] = w.x; y1[4 * kb + 1] = w.y; y1[4 * kb + 2] = w.z; y1[4 * kb + 3] = w.w;
    }
    const float4* hb4 = (const float4*)hb;
    const float4* w2b4 = (const float4*)w2b;
    float4 h0c = hb4[pp * 9];
    float4 h1c = hb4[(16 + pp) * 9];
#pragma unroll
    for (int jb = 0; jb < 8; ++jb) {
      float4 h0n, h1n;
      if (jb < 7) {
        h0n = hb4[pp * 9 + jb + 1];
        h1n = hb4[(16 + pp) * 9 + jb + 1];
      }
      float h0a[4] = {h0c.x, h0c.y, h0c.z, h0c.w};
      float h1a[4] = {h1c.x, h1c.y, h1c.z, h1c.w};
#pragma unroll
      for (int jj = 0; jj < 4; ++jj) {
        const int j = 4 * jb + jj;
#pragma unroll
        for (int kb = 0; kb < 4; ++kb) {
          float4 w = w2b4[16 * j + 4 * q + kb];  // q 2-way banks: free
          y0[4 * kb]     += h0a[jj] * w.x; y0[4 * kb + 1] += h0a[jj] * w.y;
          y0[4 * kb + 2] += h0a[jj] * w.z; y0[4 * kb + 3] += h0a[jj] * w.w;
          y1[4 * kb]     += h1a[jj] * w.x; y1[4 * kb + 1] += h1a[jj] * w.y;
          y1[4 * kb + 2] += h1a[jj] * w.z; y1[4 * kb + 3] += h1a[jj] * w.w;
        }
      }
      h0c = h0n; h1c = h1n;
    }
#pragma unroll
    for (int k = 0; k < 16; ++k) y1[k] = has2 ? y1[k] : y0[k];

    // pooled stats + chMLP layer1 partials (thread-local over 16 ch)
    float ha[16] = {0}, hm[16] = {0};
    const float kf = has2 ? 30.0f : 31.0f;     // 32 - nocc
    const float inv32 = 1.0f / 32.0f;
    const float4* c04 = (const float4*)c0b;
#pragma unroll
    for (int kb = 0; kb < 4; ++kb) {
      float4 cq = c04[q * 4 + kb];
      float c0a[4] = {cq.x, cq.y, cq.z, cq.w};
#pragma unroll
      for (int i = 0; i < 4; ++i) {
        const int k = 4 * kb + i;
        const float c0v = c0a[i];
        const float sumy = y0[k] + (has2 ? y1[k] : 0.0f);
        const float avg = fmaf(c0v, kf, sumy) * inv32;
        const float mxv = fmaxf(fmaxf(y0[k], y1[k]), c0v);
#pragma unroll
        for (int jb = 0; jb < 4; ++jb) {
          float4 w = wc1g[4 * k + jb];           // global/L1, imm offsets
          ha[4 * jb]     += avg * w.x; ha[4 * jb + 1] += avg * w.y;
          ha[4 * jb + 2] += avg * w.z; ha[4 * jb + 3] += avg * w.w;
          hm[4 * jb]     += mxv * w.x; hm[4 * jb + 1] += mxv * w.y;
          hm[4 * jb + 2] += mxv * w.z; hm[4 * jb + 3] += mxv * w.w;
        }
      }
    }
    // quad-reduce partials, bias, relu, combine pools
    float g[16];
    const float4* bc14 = (const float4*)bc1b;
#pragma unroll
    for (int jb = 0; jb < 4; ++jb) {
      float4 bb = bc14[jb];
      float bba[4] = {bb.x, bb.y, bb.z, bb.w};
#pragma unroll
      for (int i = 0; i < 4; ++i) {
        const int j = 4 * jb + i;
        const float sa = qsum4(ha[j]) + bba[i];
        const float sm = qsum4(hm[j]) + bba[i];
        g[j] = fmaxf(sa, 0.0f) + fmaxf(sm, 0.0f);
      }
    }

    // chMLP layer2 -> attc; bin-column partial reductions
    float attc[16];
    float sc = 0.0f, mc = -3.0e38f;
    float sy0 = 0.0f, my0 = -3.0e38f, sy1 = 0.0f, my1 = -3.0e38f;
    const float4* bc24 = (const float4*)bc2b;
#pragma unroll
    for (int kb = 0; kb < 4; ++kb) {
      float4 cq = c04[q * 4 + kb];
      float4 bq = bc24[q * 4 + kb];
      float c0a[4] = {cq.x, cq.y, cq.z, cq.w};
      float b2a[4] = {bq.x, bq.y, bq.z, bq.w};
#pragma unroll
      for (int i = 0; i < 4; ++i) {
        const int k = 4 * kb + i;
        float pre = 2.0f * b2a[i];
#pragma unroll
        for (int jb = 0; jb < 4; ++jb) {
          float4 w = wc2g[4 * k + jb];           // global/L1, imm offsets
          pre += g[4 * jb] * w.x + g[4 * jb + 1] * w.y +
                 g[4 * jb + 2] * w.z + g[4 * jb + 3] * w.w;
        }
        const float a = sgm(pre);
        attc[k] = a;
        const float pc0 = a * c0a[i], py0 = a * y0[k], py1 = a * y1[k];
        sc += pc0;  mc = fmaxf(mc, pc0);
        sy0 += py0; my0 = fmaxf(my0, py0);
        sy1 += py1; my1 = fmaxf(my1, py1);
      }
    }
    sc = qsum4(sc);   mc = qmax4(mc);
    sy0 = qsum4(sy0); my0 = qmax4(my0);
    sy1 = qsum4(sy1); my1 = qmax4(my1);

    // analytic conv over 32 bins, 8 bins per lane, quad-combined
    const float inv64 = 1.0f / 64.0f;
    const float Mn = sc * inv64, Mx = mc;
    const float dm0 = (sy0 - sc) * inv64, dx0 = my0 - mc;
    const float dm1 = (sy1 - sc) * inv64, dx1 = my1 - mc;
    const float bspr = bsp[0];
    const float2* ws2 = (const float2*)wsmx;
    const float2* wt2 = (const float2*)wtab;
    float maxE = -3.0e38f, minE = 3.0e38f, sv0 = -3.0e38f, sv1 = -3.0e38f;
#pragma unroll
    for (int k = 0; k < 8; ++k) {
      const int b = 8 * q + k;
      float2 ws = ws2[b];
      float acc = bspr + Mn * ws.x + Mx * ws.y;
      int k0 = b0 - b + 3;  k0 = ((unsigned)k0 <= 6u) ? k0 : 7;
      int k1 = b1e - b + 3; k1 = ((unsigned)k1 <= 6u) ? k1 : 7;
      float2 w0 = wt2[k0];
      float2 w1v = wt2[k1];
      acc += dm0 * w0.x + dx0 * w0.y + dm1 * w1v.x + dx1 * w1v.y;
      const bool o0 = (b == b0), o1 = (b == b1e);
      const bool oc = o0 || o1;
      maxE = fmaxf(maxE, oc ? -3.0e38f : acc);
      minE = fminf(minE, oc ?  3.0e38f : acc);
      sv0 = o0 ? acc : sv0;
      sv1 = o1 ? acc : sv1;
    }
    maxE = qmax4(maxE); minE = qmin4(minE);
    sv0 = qmax4(sv0);   sv1 = qmax4(sv1);
    const float sig0 = sgm(sv0);
    const float sig1 = has2 ? sgm(sv1) : sig0;
    const float sE = sgm(maxE), sI = sgm(minE);

    // epilogue: final max over bins, stores
    if (pg < U) {
      float4* ov = (float4*)(out + (size_t)pg * CO + 16 * q);
#pragma unroll
      for (int kb = 0; kb < 4; ++kb) {
        float4 cq = c04[q * 4 + kb];
        float c0a[4] = {cq.x, cq.y, cq.z, cq.w};
        float rr[4];
#pragma unroll
        for (int i = 0; i < 4; ++i) {
          const int k = 4 * kb + i;
          const float c0v = c0a[i];
          const float sel = (c0v >= 0.0f) ? sE : sI;
          const float m = fmaxf(fmaxf(y0[k] * sig0, y1[k] * sig1), c0v * sel);
          rr[i] = attc[k] * m;
        }
        float4 r; r.x = rr[0]; r.y = rr[1]; r.z = rr[2]; r.w = rr[3];
        ov[kb] = r;
      }
      if (q == 0) out[(size_t)U * CO + pg] = has2 ? 1.0f : 0.0f;
    }

    // ---- next trip's vbuf fill must have landed before reuse
    drain_vm();
  }
}

extern "C" void kernel_launch(void* const* d_in, const int* in_sizes, int n_in,
                              void* d_out, int out_size, void* d_ws, size_t ws_size,
                              hipStream_t stream) {
  const float* vf      = (const float*)d_in[0];
  const int*   vcoord  = (const int*)d_in[1];
  // d_in[2] = unq_coords (unused: identity)
  const int*   unq_inv = (const int*)d_in[3];
  const int*   unq_cnt = (const int*)d_in[4];
  const float* W1  = (const float*)d_in[5];
  const float* b1  = (const float*)d_in[6];
  const float* W2  = (const float*)d_in[7];
  const float* b2  = (const float*)d_in[8];
  const float* Wc1 = (const float*)d_in[9];
  const float* bc1 = (const float*)d_in[10];
  const float* Wc2 = (const float*)d_in[11];
  const float* bc2 = (const float*)d_in[12];
  const float* Wsp = (const float*)d_in[13];
  const float* bsp = (const float*)d_in[14];

  const int N = in_sizes[3];   // voxels
  const int U = in_sizes[4];   // pillars

  float* pvox = (float*)d_ws;                  // 2U records x 32B
  float* wc2t = pvox + 16 * (size_t)U;         // Wc2^T staging (4KB)

  pack_kernel<<<(N + 255) / 256, 256, 0, stream>>>(vf, vcoord, unq_inv, pvox, N,
                                                   Wc2, wc2t);

  const int ngroups = (U + 15) / 16;      // 16 pillars per wave-trip
  int blocks = 1280;                      // 5 blocks/CU if VGPR<=96 (LDS 31.5KB)
  const int maxBlocks = (ngroups + 3) / 4;
  if (blocks > maxBlocks) blocks = maxBlocks;
  const int totalWaves = blocks * 4;
  cbam_kernel<<<blocks, 256, 0, stream>>>(
      pvox, unq_cnt, W1, b1, W2, b2, Wc1, bc1, wc2t, bc2, Wsp, bsp,
      (float*)d_out, U, ngroups, totalWaves);
}

// Round 5
// 221.907 us; speedup vs baseline: 3.8474x; 2.2539x over previous
//
#include <hip/hip_runtime.h>
#include <math.h>

// CBAM pillar kernel for MI355X (gfx950) — round 20.
//
// R18: launch_bounds(256,5) -> VGPR 48, total spill, 774us.
// R19: no bound -> LICM hoisted the (loop-invariant) global Wc1/Wc2^T
//      loads out of the trip loop, tried to register-cache 2x64 float4
//      -> VGPR 256 + spill, 459us.
// R20: defeat LICM with a no-op asm launder of the weight BASE pointers
//      inside the trip loop ("+s": they stay in SGPR pairs, 0 VGPR cost).
//      Loads re-issue per trip, hit L1 (8KB hot).  Host picks grid from
//      hipFuncGetAttributes.numRegs: 5 blocks/CU iff VGPR<=102 (512/SIMD
//      pool / 5 waves), else exact R15 capacity (4 blocks/CU).

#define CO 64

__device__ __forceinline__ float sgm(float x) {
  return 1.0f / (1.0f + __expf(-x));
}
template <int PAT>
__device__ __forceinline__ float qadd(float s) {
  int t = __builtin_amdgcn_update_dpp(0, __builtin_bit_cast(int, s),
                                      PAT, 0xf, 0xf, true);
  return s + __builtin_bit_cast(float, t);
}
template <int PAT>
__device__ __forceinline__ float qmaxd(float m) {
  int t = __builtin_amdgcn_update_dpp(__builtin_bit_cast(int, m),
                                      __builtin_bit_cast(int, m),
                                      PAT, 0xf, 0xf, false);
  return fmaxf(m, __builtin_bit_cast(float, t));
}
template <int PAT>
__device__ __forceinline__ float qmind(float m) {
  int t = __builtin_amdgcn_update_dpp(__builtin_bit_cast(int, m),
                                      __builtin_bit_cast(int, m),
                                      PAT, 0xf, 0xf, false);
  return fminf(m, __builtin_bit_cast(float, t));
}
// full exchange within each 4-lane quad: 0xB1=[1,0,3,2], 0x4E=[2,3,0,1]
__device__ __forceinline__ float qsum4(float s) { return qadd<0x4E>(qadd<0xB1>(s)); }
__device__ __forceinline__ float qmax4(float m) { return qmaxd<0x4E>(qmaxd<0xB1>(m)); }
__device__ __forceinline__ float qmin4(float m) { return qmind<0x4E>(qmind<0xB1>(m)); }
__device__ __forceinline__ void drain_lds() {
  __builtin_amdgcn_wave_barrier();
  __builtin_amdgcn_s_waitcnt(0xC07F);   // lgkmcnt(0)
  __builtin_amdgcn_wave_barrier();
}
__device__ __forceinline__ void drain_vm() {
  __builtin_amdgcn_wave_barrier();
  __builtin_amdgcn_s_waitcnt(0x0F70);   // vmcnt(0)
  __builtin_amdgcn_wave_barrier();
}

// per-voxel: pvox[2p+slot] = {vf[5], bits(bin), 0, 0}  (32B records)
// + stage Wc2^T (64x16) into ws so cbam reads it k-major from global/L1.
__global__ __launch_bounds__(256) void pack_kernel(
    const float* __restrict__ vf, const int* __restrict__ vcoord,
    const int* __restrict__ unq_inv, float* __restrict__ pvox, int n,
    const float* __restrict__ Wc2, float* __restrict__ wc2t) {
  int i = blockIdx.x * blockDim.x + threadIdx.x;
  if (i < 1024) wc2t[i] = Wc2[(i & 15) * 64 + (i >> 4)];  // [ch][j] <- [j][ch]
  if (i >= n) return;
  int p = unq_inv[i];
  int slot = (i > 0 && unq_inv[i - 1] == p) ? 1 : 0;
  float* dst = pvox + 8 * (size_t)(2 * p + slot);
#pragma unroll
  for (int k = 0; k < 5; ++k) dst[k] = vf[5 * i + k];
  ((int*)dst)[5] = vcoord[4 * i + 1];
}

__global__ __launch_bounds__(256) void cbam_kernel(
    const float* __restrict__ pvox, const int* __restrict__ unq_cnt,
    const float* __restrict__ W1, const float* __restrict__ b1,
    const float* __restrict__ W2, const float* __restrict__ b2,
    const float* __restrict__ Wc1, const float* __restrict__ bc1,
    const float* __restrict__ wc2t, const float* __restrict__ bc2,
    const float* __restrict__ Wsp, const float* __restrict__ bsp,
    float* __restrict__ out, int U, int ngroups, int totalWaves) {
  __shared__ __align__(16) float w2b[2048];   // 32 x 64 (stride 64)
  __shared__ __align__(16) float c0b[64], b2b[64], bc2b[64], bc1b[16];
  __shared__ __align__(16) float wsmx[64];    // float2[32] window sums
  __shared__ __align__(16) float wtab[16];    // float2[8] taps, [7]={0,0}
  __shared__ __align__(16) float hbuf[4][1152];  // per-wave 32 x stride 36
  __shared__ __align__(16) float vbuf[4][256];   // per-wave voxel block (1KB)

  const int tid = threadIdx.x;

  // ---- stage weights to LDS (once per block; persistent blocks)
  for (int i = tid; i < 2048; i += 256) w2b[i] = W2[i];
  if (tid < 64) { b2b[tid] = b2[tid]; bc2b[tid] = bc2[tid]; }
  if (tid < 16) bc1b[tid] = bc1[tid];
  if (tid < 32) {
    float sm = 0.0f, sx = 0.0f;
    for (int k = 0; k < 7; ++k)
      if ((unsigned)(tid + k - 3) < 32u) { sm += Wsp[k]; sx += Wsp[7 + k]; }
    wsmx[2 * tid] = sm; wsmx[2 * tid + 1] = sx;
  }
  if (tid < 8) {
    float a = 0.0f, b = 0.0f;
    if (tid < 7) { a = Wsp[tid]; b = Wsp[7 + tid]; }
    wtab[2 * tid] = a; wtab[2 * tid + 1] = b;
  }
  __syncthreads();
  if (tid < 64) {                      // c0[ch] = b2 + relu(b1) @ W2
    float c = b2b[tid];
    for (int j = 0; j < 32; ++j) c += fmaxf(b1[j], 0.0f) * w2b[j * 64 + tid];
    c0b[tid] = c;
  }
  __syncthreads();

  const int wv = tid >> 6, lane = tid & 63;
  int grp = blockIdx.x * 4 + wv;       // static grid-stride schedule
  if (grp >= ngroups) return;          // all __syncthreads are above

  float* const hb = hbuf[wv];
  float* const vb = vbuf[wv];
  float4* const vb4 = (float4*)vb;

  const int j32 = lane & 31, vh = lane >> 5;
  const int q = lane & 3, pp = lane >> 2;
  const float4* pv4 = (const float4*)pvox;
  const int f4max = 4 * U - 1;         // pvox has 4U float4 entries

  // uniform weight bases (laundered per trip to defeat LICM; stay in SGPRs)
  const float4* wc1g = (const float4*)Wc1;
  const float4* wc2g = (const float4*)wc2t;
  const float* w1p = W1;
  const float* b1p = b1;
  const int qo = q << 6;               // per-lane float4 offset (q*1024B)

  // ---- prologue: async-stage trip-0 voxel block straight to LDS
  {
    int idx = 64 * grp + lane;
    idx = idx < f4max ? idx : f4max;
    __builtin_amdgcn_global_load_lds(
        (const __attribute__((address_space(1))) void*)(pv4 + idx),
        (__attribute__((address_space(3))) void*)vb4, 16, 0, 0);
  }
  drain_vm();

  for (; grp < ngroups; grp += totalWaves) {
    // defeat LICM: weight bases formally redefined every trip (no-op).
    asm volatile("" : "+s"(wc1g), "+s"(wc2g), "+s"(w1p), "+s"(b1p));

    const int P0 = grp * 16;           // 16 pillars this trip

    // ---- metadata (cnt global; bins from current vbuf) hoisted
    const int pg = P0 + pp;
    const int pc = pg < U ? pg : (U - 1);
    const int cnt = unq_cnt[pc];
    const int* vbi = (const int*)vb;
    const int b0 = vbi[(2 * pp) * 8 + 5] & 31;
    const int b1raw = vbi[(2 * pp + 1) * 8 + 5];

    // ---- phase 1: layer1 from vbuf.  lane = (j32, voxel-half vh)
    // w1/b1 reloaded per trip (L1-hot) to keep persistent VGPRs low.
    {
      float w1r[5];
#pragma unroll
      for (int i = 0; i < 5; ++i) w1r[i] = w1p[i * 32 + j32];
      const float b1r = b1p[j32];
      const float4* vb4c = (const float4*)vb;
#pragma unroll
      for (int v = 0; v < 16; ++v) {
        const int rec = 16 * vh + v;
        float4 g1 = vb4c[2 * rec];       // uniform per half -> broadcast
        float4 g2 = vb4c[2 * rec + 1];
        float h = b1r + g1.x * w1r[0] + g1.y * w1r[1] + g1.z * w1r[2] +
                  g1.w * w1r[3] + g2.x * w1r[4];
        const int row = (v & 1) * 16 + 8 * vh + (v >> 1);
        hb[row * 36 + j32] = fmaxf(h, 0.0f);
      }
    }
    drain_lds();

    // ---- vbuf is dead now: issue next trip's fill straight to LDS.
    // Lands during phase 2; vmcnt(0) at trip end guards the reuse.
    {
      const int nxt = grp + totalWaves;
      if (nxt < ngroups) {
        int nidx = 64 * nxt + lane;
        nidx = nidx < f4max ? nidx : f4max;
        __builtin_amdgcn_global_load_lds(
            (const __attribute__((address_space(1))) void*)(pv4 + nidx),
            (__attribute__((address_space(3))) void*)vb4, 16, 0, 0);
      }
    }

    // ---- phase 2: lane = (pillar pp, ch-quad q); channels 16q..16q+15
    const bool has2 = (cnt >= 2);
    const int b1e = has2 ? (b1raw & 31) : 64;

    // layer2
    float y0[16], y1[16];
    const float4* b2b4 = (const float4*)b2b;
#pragma unroll
    for (int kb = 0; kb < 4; ++kb) {
      float4 w = b2b4[q * 4 + kb];
      y0[4 * kb] = w.x; y0[4 * kb + 1] = w.y; y0[4 * kb + 2] = w.z; y0[4 * kb + 3] = w.w;
      y1[4 * kb] = w.x; y1[4 * kb + 1] = w.y; y1[4 * kb + 2] = w.z; y1[4 * kb + 3] = w.w;
    }
    const float4* hb4 = (const float4*)hb;
    const float4* w2b4 = (const float4*)w2b;
    float4 h0c = hb4[pp * 9];
    float4 h1c = hb4[(16 + pp) * 9];
#pragma unroll
    for (int jb = 0; jb < 8; ++jb) {
      float4 h0n, h1n;
      if (jb < 7) {
        h0n = hb4[pp * 9 + jb + 1];
        h1n = hb4[(16 + pp) * 9 + jb + 1];
      }
      float h0a[4] = {h0c.x, h0c.y, h0c.z, h0c.w};
      float h1a[4] = {h1c.x, h1c.y, h1c.z, h1c.w};
#pragma unroll
      for (int jj = 0; jj < 4; ++jj) {
        const int j = 4 * jb + jj;
#pragma unroll
        for (int kb = 0; kb < 4; ++kb) {
          float4 w = w2b4[16 * j + 4 * q + kb];  // q 2-way banks: free
          y0[4 * kb]     += h0a[jj] * w.x; y0[4 * kb + 1] += h0a[jj] * w.y;
          y0[4 * kb + 2] += h0a[jj] * w.z; y0[4 * kb + 3] += h0a[jj] * w.w;
          y1[4 * kb]     += h1a[jj] * w.x; y1[4 * kb + 1] += h1a[jj] * w.y;
          y1[4 * kb + 2] += h1a[jj] * w.z; y1[4 * kb + 3] += h1a[jj] * w.w;
        }
      }
      h0c = h0n; h1c = h1n;
    }
#pragma unroll
    for (int k = 0; k < 16; ++k) y1[k] = has2 ? y1[k] : y0[k];

    // pooled stats + chMLP layer1 partials (thread-local over 16 ch)
    float ha[16] = {0}, hm[16] = {0};
    const float kf = has2 ? 30.0f : 31.0f;     // 32 - nocc
    const float inv32 = 1.0f / 32.0f;
    const float4* c04 = (const float4*)c0b;
#pragma unroll
    for (int kb = 0; kb < 4; ++kb) {
      float4 cq = c04[q * 4 + kb];
      float c0a[4] = {cq.x, cq.y, cq.z, cq.w};
#pragma unroll
      for (int i = 0; i < 4; ++i) {
        const int k = 4 * kb + i;
        const float c0v = c0a[i];
        const float sumy = y0[k] + (has2 ? y1[k] : 0.0f);
        const float avg = fmaf(c0v, kf, sumy) * inv32;
        const float mxv = fmaxf(fmaxf(y0[k], y1[k]), c0v);
#pragma unroll
        for (int jb = 0; jb < 4; ++jb) {
          float4 w = wc1g[qo + 4 * k + jb];      // global/L1, SGPR base
          ha[4 * jb]     += avg * w.x; ha[4 * jb + 1] += avg * w.y;
          ha[4 * jb + 2] += avg * w.z; ha[4 * jb + 3] += avg * w.w;
          hm[4 * jb]     += mxv * w.x; hm[4 * jb + 1] += mxv * w.y;
          hm[4 * jb + 2] += mxv * w.z; hm[4 * jb + 3] += mxv * w.w;
        }
      }
    }
    // quad-reduce partials, bias, relu, combine pools
    float g[16];
    const float4* bc14 = (const float4*)bc1b;
#pragma unroll
    for (int jb = 0; jb < 4; ++jb) {
      float4 bb = bc14[jb];
      float bba[4] = {bb.x, bb.y, bb.z, bb.w};
#pragma unroll
      for (int i = 0; i < 4; ++i) {
        const int j = 4 * jb + i;
        const float sa = qsum4(ha[j]) + bba[i];
        const float sm = qsum4(hm[j]) + bba[i];
        g[j] = fmaxf(sa, 0.0f) + fmaxf(sm, 0.0f);
      }
    }

    // chMLP layer2 -> attc; bin-column partial reductions
    float attc[16];
    float sc = 0.0f, mc = -3.0e38f;
    float sy0 = 0.0f, my0 = -3.0e38f, sy1 = 0.0f, my1 = -3.0e38f;
    const float4* bc24 = (const float4*)bc2b;
#pragma unroll
    for (int kb = 0; kb < 4; ++kb) {
      float4 cq = c04[q * 4 + kb];
      float4 bq = bc24[q * 4 + kb];
      float c0a[4] = {cq.x, cq.y, cq.z, cq.w};
      float b2a[4] = {bq.x, bq.y, bq.z, bq.w};
#pragma unroll
      for (int i = 0; i < 4; ++i) {
        const int k = 4 * kb + i;
        float pre = 2.0f * b2a[i];
#pragma unroll
        for (int jb = 0; jb < 4; ++jb) {
          float4 w = wc2g[qo + 4 * k + jb];      // global/L1, SGPR base
          pre += g[4 * jb] * w.x + g[4 * jb + 1] * w.y +
                 g[4 * jb + 2] * w.z + g[4 * jb + 3] * w.w;
        }
        const float a = sgm(pre);
        attc[k] = a;
        const float pc0 = a * c0a[i], py0 = a * y0[k], py1 = a * y1[k];
        sc += pc0;  mc = fmaxf(mc, pc0);
        sy0 += py0; my0 = fmaxf(my0, py0);
        sy1 += py1; my1 = fmaxf(my1, py1);
      }
    }
    sc = qsum4(sc);   mc = qmax4(mc);
    sy0 = qsum4(sy0); my0 = qmax4(my0);
    sy1 = qsum4(sy1); my1 = qmax4(my1);

    // analytic conv over 32 bins, 8 bins per lane, quad-combined
    const float inv64 = 1.0f / 64.0f;
    const float Mn = sc * inv64, Mx = mc;
    const float dm0 = (sy0 - sc) * inv64, dx0 = my0 - mc;
    const float dm1 = (sy1 - sc) * inv64, dx1 = my1 - mc;
    const float bspr = bsp[0];
    const float2* ws2 = (const float2*)wsmx;
    const float2* wt2 = (const float2*)wtab;
    float maxE = -3.0e38f, minE = 3.0e38f, sv0 = -3.0e38f, sv1 = -3.0e38f;
#pragma unroll
    for (int k = 0; k < 8; ++k) {
      const int b = 8 * q + k;
      float2 ws = ws2[b];
      float acc = bspr + Mn * ws.x + Mx * ws.y;
      int k0 = b0 - b + 3;  k0 = ((unsigned)k0 <= 6u) ? k0 : 7;
      int k1 = b1e - b + 3; k1 = ((unsigned)k1 <= 6u) ? k1 : 7;
      float2 w0 = wt2[k0];
      float2 w1v = wt2[k1];
      acc += dm0 * w0.x + dx0 * w0.y + dm1 * w1v.x + dx1 * w1v.y;
      const bool o0 = (b == b0), o1 = (b == b1e);
      const bool oc = o0 || o1;
      maxE = fmaxf(maxE, oc ? -3.0e38f : acc);
      minE = fminf(minE, oc ?  3.0e38f : acc);
      sv0 = o0 ? acc : sv0;
      sv1 = o1 ? acc : sv1;
    }
    maxE = qmax4(maxE); minE = qmin4(minE);
    sv0 = qmax4(sv0);   sv1 = qmax4(sv1);
    const float sig0 = sgm(sv0);
    const float sig1 = has2 ? sgm(sv1) : sig0;
    const float sE = sgm(maxE), sI = sgm(minE);

    // epilogue: final max over bins, stores
    if (pg < U) {
      float4* ov = (float4*)(out + (size_t)pg * CO + 16 * q);
#pragma unroll
      for (int kb = 0; kb < 4; ++kb) {
        float4 cq = c04[q * 4 + kb];
        float c0a[4] = {cq.x, cq.y, cq.z, cq.w};
        float rr[4];
#pragma unroll
        for (int i = 0; i < 4; ++i) {
          const int k = 4 * kb + i;
          const float c0v = c0a[i];
          const float sel = (c0v >= 0.0f) ? sE : sI;
          const float m = fmaxf(fmaxf(y0[k] * sig0, y1[k] * sig1), c0v * sel);
          rr[i] = attc[k] * m;
        }
        float4 r; r.x = rr[0]; r.y = rr[1]; r.z = rr[2]; r.w = rr[3];
        ov[kb] = r;
      }
      if (q == 0) out[(size_t)U * CO + pg] = has2 ? 1.0f : 0.0f;
    }

    // ---- next trip's vbuf fill must have landed before reuse
    drain_vm();
  }
}

extern "C" void kernel_launch(void* const* d_in, const int* in_sizes, int n_in,
                              void* d_out, int out_size, void* d_ws, size_t ws_size,
                              hipStream_t stream) {
  const float* vf      = (const float*)d_in[0];
  const int*   vcoord  = (const int*)d_in[1];
  // d_in[2] = unq_coords (unused: identity)
  const int*   unq_inv = (const int*)d_in[3];
  const int*   unq_cnt = (const int*)d_in[4];
  const float* W1  = (const float*)d_in[5];
  const float* b1  = (const float*)d_in[6];
  const float* W2  = (const float*)d_in[7];
  const float* b2  = (const float*)d_in[8];
  const float* Wc1 = (const float*)d_in[9];
  const float* bc1 = (const float*)d_in[10];
  const float* Wc2 = (const float*)d_in[11];
  const float* bc2 = (const float*)d_in[12];
  const float* Wsp = (const float*)d_in[13];
  const float* bsp = (const float*)d_in[14];

  const int N = in_sizes[3];   // voxels
  const int U = in_sizes[4];   // pillars

  float* pvox = (float*)d_ws;                  // 2U records x 32B
  float* wc2t = pvox + 16 * (size_t)U;         // Wc2^T staging (4KB)

  pack_kernel<<<(N + 255) / 256, 256, 0, stream>>>(vf, vcoord, unq_inv, pvox, N,
                                                   Wc2, wc2t);

  // pick resident blocks/CU from compiled VGPR count (once; host-side query
  // is graph-capture safe — no alloc/sync involved).
  static int blocksPerCU = 0;
  if (blocksPerCU == 0) {
    hipFuncAttributes a;
    blocksPerCU = 4;
    if (hipFuncGetAttributes(&a, (const void*)cbam_kernel) == hipSuccess &&
        a.numRegs > 0 && a.numRegs <= 102)
      blocksPerCU = 5;                 // 5 waves/SIMD fits (512-reg pool)
  }

  const int ngroups = (U + 15) / 16;      // 16 pillars per wave-trip
  int blocks = 256 * blocksPerCU;         // exactly-resident persistent grid
  const int maxBlocks = (ngroups + 3) / 4;
  if (blocks > maxBlocks) blocks = maxBlocks;
  const int totalWaves = blocks * 4;
  cbam_kernel<<<blocks, 256, 0, stream>>>(
      pvox, unq_cnt, W1, b1, W2, b2, Wc1, bc1, wc2t, bc2, Wsp, bsp,
      (float*)d_out, U, ngroups, totalWaves);
}

// Round 6
// 137.665 us; speedup vs baseline: 6.2018x; 1.6119x over previous
//
#include <hip/hip_runtime.h>
#include <math.h>

// CBAM pillar kernel for MI355X (gfx950) — round 21.
//
// R15=61us (all-LDS weights, static schedule).  R16-R20 established:
//  - schedule is already work-balanced per SIMD (6.1 trips/SIMD); the 43%
//    VALU idle is per-trip work/stall, not tail (R16/R17 null results).
//  - weights must live in LDS (R19 LICM reg-explosion / R20 exposed-latency
//    both lose vs LDS re-reads).
// R21 attacks the dominant per-trip cost: layer2 = 1024 v_fma + 128
// ds_read_b128 per lane-trip, MfmaUtil 0.  It is a 32x32 @ 32x64 K=32 GEMM
// -> v_mfma_f32_16x16x32_bf16 with 4-term bf16 hi/lo RTN split (err ~1e-4).
// hbuf (18KB) dies: phase1 builds A-fragments in registers.  A small
// float2 ybuf (4.3KB/wave) transposes MFMA C-layout (col=lane&15,
// row=4*(lane>>4)+reg; voxel pairs in adjacent regs) back to the (pp,q)
// layout so all post-processing is byte-identical to R15.  W2 pre-split
// to bf16 B-fragments once per block.  LDS 39808 -> 4 blocks/CU.

#define CO 64

typedef __attribute__((ext_vector_type(8))) short s16x8;
typedef __attribute__((ext_vector_type(4))) float f32x4;
union ABu { uint4 u4; s16x8 s; };

__device__ __forceinline__ float sgm(float x) {
  return 1.0f / (1.0f + __expf(-x));
}
template <int PAT>
__device__ __forceinline__ float qadd(float s) {
  int t = __builtin_amdgcn_update_dpp(0, __builtin_bit_cast(int, s),
                                      PAT, 0xf, 0xf, true);
  return s + __builtin_bit_cast(float, t);
}
template <int PAT>
__device__ __forceinline__ float qmaxd(float m) {
  int t = __builtin_amdgcn_update_dpp(__builtin_bit_cast(int, m),
                                      __builtin_bit_cast(int, m),
                                      PAT, 0xf, 0xf, false);
  return fmaxf(m, __builtin_bit_cast(float, t));
}
template <int PAT>
__device__ __forceinline__ float qmind(float m) {
  int t = __builtin_amdgcn_update_dpp(__builtin_bit_cast(int, m),
                                      __builtin_bit_cast(int, m),
                                      PAT, 0xf, 0xf, false);
  return fminf(m, __builtin_bit_cast(float, t));
}
// full exchange within each 4-lane quad: 0xB1=[1,0,3,2], 0x4E=[2,3,0,1]
__device__ __forceinline__ float qsum4(float s) { return qadd<0x4E>(qadd<0xB1>(s)); }
__device__ __forceinline__ float qmax4(float m) { return qmaxd<0x4E>(qmaxd<0xB1>(m)); }
__device__ __forceinline__ float qmin4(float m) { return qmind<0x4E>(qmind<0xB1>(m)); }
__device__ __forceinline__ void drain_lds() {
  __builtin_amdgcn_wave_barrier();
  __builtin_amdgcn_s_waitcnt(0xC07F);   // lgkmcnt(0)
  __builtin_amdgcn_wave_barrier();
}
__device__ __forceinline__ void drain_vm() {
  __builtin_amdgcn_wave_barrier();
  __builtin_amdgcn_s_waitcnt(0x0F70);   // vmcnt(0)
  __builtin_amdgcn_wave_barrier();
}

// RTN bf16: rounded value sits in the TOP 16 bits of the return.
__device__ __forceinline__ uint rtn16(float f) {
  uint u = __builtin_bit_cast(uint, f);
  return u + 0x7fffu + ((u >> 16) & 1u);
}
// e[8] (k-order) -> hi/lo bf16 fragments; u32[p] packs (e[2p], e[2p+1]).
__device__ __forceinline__ void mk_frag(const float* e, ABu& hi, ABu& lo) {
  uint h[4], l[4];
#pragma unroll
  for (int p = 0; p < 4; ++p) {
    uint r0 = rtn16(e[2 * p]), r1 = rtn16(e[2 * p + 1]);
    h[p] = (r0 >> 16) | (r1 & 0xffff0000u);
    float d0 = e[2 * p]     - __builtin_bit_cast(float, r0 & 0xffff0000u);
    float d1 = e[2 * p + 1] - __builtin_bit_cast(float, r1 & 0xffff0000u);
    uint s0 = rtn16(d0), s1 = rtn16(d1);
    l[p] = (s0 >> 16) | (s1 & 0xffff0000u);
  }
  hi.u4 = make_uint4(h[0], h[1], h[2], h[3]);
  lo.u4 = make_uint4(l[0], l[1], l[2], l[3]);
}

// per-voxel: pvox[2p+slot] = {vf[5], bits(bin), 0, 0}  (32B records)
__global__ __launch_bounds__(256) void pack_kernel(
    const float* __restrict__ vf, const int* __restrict__ vcoord,
    const int* __restrict__ unq_inv, float* __restrict__ pvox, int n) {
  int i = blockIdx.x * blockDim.x + threadIdx.x;
  if (i >= n) return;
  int p = unq_inv[i];
  int slot = (i > 0 && unq_inv[i - 1] == p) ? 1 : 0;
  float* dst = pvox + 8 * (size_t)(2 * p + slot);
#pragma unroll
  for (int k = 0; k < 5; ++k) dst[k] = vf[5 * i + k];
  ((int*)dst)[5] = vcoord[4 * i + 1];
}

__global__ __launch_bounds__(256) void cbam_kernel(
    const float* __restrict__ pvox, const int* __restrict__ unq_cnt,
    const float* __restrict__ W1, const float* __restrict__ b1,
    const float* __restrict__ W2, const float* __restrict__ b2,
    const float* __restrict__ Wc1, const float* __restrict__ bc1,
    const float* __restrict__ Wc2, const float* __restrict__ bc2,
    const float* __restrict__ Wsp, const float* __restrict__ bsp,
    float* __restrict__ out, int U, int ngroups, int totalWaves) {
  __shared__ __align__(16) uint4 w2fh[256], w2fl[256];   // W2 bf16 B-frags
  __shared__ __align__(16) float w1b[160], b1b[32];
  __shared__ __align__(16) float wc1b[1024];  // k-major: [(4k+q)*16 + j]
  __shared__ __align__(16) float wc2b[1024];  // k-major Wc2^T
  __shared__ __align__(16) float c0b[64], b2b[64], bc2b[64], bc1b[16];
  __shared__ __align__(16) float wsmx[64];    // float2[32] window sums
  __shared__ __align__(16) float wtab[16];    // float2[8] taps, [7]={0,0}
  __shared__ __align__(16) float vbuf[4][256];   // per-wave voxel block (1KB)
  __shared__ __align__(16) float2 ybuf[4][544];  // per-wave 16 x 34 (transpose)

  const int tid = threadIdx.x;

  // ---- stage weights (once per block; persistent blocks)
  {  // W2 -> bf16 hi/lo B-fragments: tile nt=tid>>6, lane l=tid&63
    const int nt = tid >> 6, l = tid & 63, gg = l >> 4, cc = l & 15;
    uint hu[4], lu[4];
#pragma unroll
    for (int p = 0; p < 4; ++p) {
      float f0 = W2[(8 * gg + 2 * p)     * 64 + 16 * nt + cc];
      float f1 = W2[(8 * gg + 2 * p + 1) * 64 + 16 * nt + cc];
      uint r0 = rtn16(f0), r1 = rtn16(f1);
      hu[p] = (r0 >> 16) | (r1 & 0xffff0000u);
      float d0 = f0 - __builtin_bit_cast(float, r0 & 0xffff0000u);
      float d1 = f1 - __builtin_bit_cast(float, r1 & 0xffff0000u);
      uint s0 = rtn16(d0), s1 = rtn16(d1);
      lu[p] = (s0 >> 16) | (s1 & 0xffff0000u);
    }
    w2fh[tid] = make_uint4(hu[0], hu[1], hu[2], hu[3]);
    w2fl[tid] = make_uint4(lu[0], lu[1], lu[2], lu[3]);
  }
  if (tid < 160) w1b[tid] = W1[tid];
  if (tid < 32) b1b[tid] = b1[tid];
  for (int i = tid; i < 1024; i += 256) {
    // i = ch*16 + j, ch = 16q + k  ->  dst (4k+q)*16 + j
    int ch = i >> 4, j = i & 15, qq = ch >> 4, k = ch & 15;
    wc1b[(4 * k + qq) * 16 + j] = Wc1[i];
    wc2b[(4 * k + qq) * 16 + j] = Wc2[j * 64 + ch];
  }
  if (tid < 64) { b2b[tid] = b2[tid]; bc2b[tid] = bc2[tid]; }
  if (tid < 16) bc1b[tid] = bc1[tid];
  if (tid < 32) {
    float sm = 0.0f, sx = 0.0f;
    for (int k = 0; k < 7; ++k)
      if ((unsigned)(tid + k - 3) < 32u) { sm += Wsp[k]; sx += Wsp[7 + k]; }
    wsmx[2 * tid] = sm; wsmx[2 * tid + 1] = sx;
  }
  if (tid < 8) {
    float a = 0.0f, b = 0.0f;
    if (tid < 7) { a = Wsp[tid]; b = Wsp[7 + tid]; }
    wtab[2 * tid] = a; wtab[2 * tid + 1] = b;
  }
  __syncthreads();
  if (tid < 64) {                      // c0[ch] = b2 + relu(b1) @ W2 (f32)
    float c = b2b[tid];
    for (int j = 0; j < 32; ++j) c += fmaxf(b1b[j], 0.0f) * W2[j * 64 + tid];
    c0b[tid] = c;
  }
  __syncthreads();

  const int wv = tid >> 6, lane = tid & 63;
  int grp = blockIdx.x * 4 + wv;       // static grid-stride schedule
  if (grp >= ngroups) return;          // all __syncthreads are above

  float* const vb = vbuf[wv];
  float4* const vb4 = (float4*)vb;
  float2* const yb2 = ybuf[wv];
  float4* const yb4 = (float4*)yb2;    // pillar stride 17 float4 (272B)

  const int c16 = lane & 15, g = lane >> 4;   // MFMA lane roles
  const int q = lane & 3, pp = lane >> 2;     // post-processing roles
  const float4* pv4 = (const float4*)pvox;
  const int f4max = 4 * U - 1;         // pvox has 4U float4 entries

  // ---- prologue: async-stage trip-0 voxel block straight to LDS
  {
    int idx = 64 * grp + lane;
    idx = idx < f4max ? idx : f4max;
    __builtin_amdgcn_global_load_lds(
        (const __attribute__((address_space(1))) void*)(pv4 + idx),
        (__attribute__((address_space(3))) void*)vb4, 16, 0, 0);
  }
  drain_vm();

  for (; grp < ngroups; grp += totalWaves) {
    int ofs0 = 0;
    asm volatile("" : "+s"(ofs0));     // keep frag/LDS reads per-trip

    const int P0 = grp * 16;           // 16 pillars this trip

    // ---- metadata (cnt global; bins from current vbuf)
    const int pg = P0 + pp;
    const int pc = pg < U ? pg : (U - 1);
    const int cnt = unq_cnt[pc];
    const int* vbi = (const int*)vb;
    const int b0 = vbi[(2 * pp) * 8 + 5] & 31;
    const int b1raw = vbi[(2 * pp + 1) * 8 + 5];

    // ---- phase 1: per-lane A-fragments.  lane owns rows c16, c16+16,
    // k-chunk 8g..8g+7.  h = relu(b1 + v @ W1), split bf16 hi/lo (RTN).
    ABu ah0, al0, ah1, al1;
    {
      const float4* vb4c = (const float4*)vb;
      float4 xa = vb4c[2 * c16], xb = vb4c[2 * c16 + 1];
      float4 yc = vb4c[2 * (c16 + 16)], yd = vb4c[2 * (c16 + 16) + 1];
      float va[5] = {xa.x, xa.y, xa.z, xa.w, xb.x};
      float vc[5] = {yc.x, yc.y, yc.z, yc.w, yd.x};
      const float4* w1b4 = (const float4*)w1b;
      const float4* b1b4 = (const float4*)b1b;
      float4 bA = b1b4[ofs0 + 2 * g], bB = b1b4[ofs0 + 2 * g + 1];
      float e0[8] = {bA.x, bA.y, bA.z, bA.w, bB.x, bB.y, bB.z, bB.w};
      float e1[8] = {bA.x, bA.y, bA.z, bA.w, bB.x, bB.y, bB.z, bB.w};
#pragma unroll
      for (int d = 0; d < 5; ++d) {
        float4 w0 = w1b4[ofs0 + d * 8 + 2 * g];
        float4 w1v = w1b4[ofs0 + d * 8 + 2 * g + 1];
        e0[0] += va[d] * w0.x;  e0[1] += va[d] * w0.y;
        e0[2] += va[d] * w0.z;  e0[3] += va[d] * w0.w;
        e0[4] += va[d] * w1v.x; e0[5] += va[d] * w1v.y;
        e0[6] += va[d] * w1v.z; e0[7] += va[d] * w1v.w;
        e1[0] += vc[d] * w0.x;  e1[1] += vc[d] * w0.y;
        e1[2] += vc[d] * w0.z;  e1[3] += vc[d] * w0.w;
        e1[4] += vc[d] * w1v.x; e1[5] += vc[d] * w1v.y;
        e1[6] += vc[d] * w1v.z; e1[7] += vc[d] * w1v.w;
      }
#pragma unroll
      for (int i = 0; i < 8; ++i) {
        e0[i] = fmaxf(e0[i], 0.0f);
        e1[i] = fmaxf(e1[i], 0.0f);
      }
      mk_frag(e0, ah0, al0);
      mk_frag(e1, ah1, al1);
    }
    drain_lds();                        // vbuf reads retired

    // ---- vbuf dead: issue next trip's fill straight to LDS
    {
      const int nxt = grp + totalWaves;
      if (nxt < ngroups) {
        int nidx = 64 * nxt + lane;
        nidx = nidx < f4max ? nidx : f4max;
        __builtin_amdgcn_global_load_lds(
            (const __attribute__((address_space(1))) void*)(pv4 + nidx),
            (__attribute__((address_space(3))) void*)vb4, 16, 0, 0);
      }
    }

    // ---- layer2 via MFMA, two 32-ch halves through the ybuf transpose
    float y0[16], y1[16];
#pragma unroll
    for (int half = 0; half < 2; ++half) {
      f32x4 acc[2][2];
#pragma unroll
      for (int mt = 0; mt < 2; ++mt)
#pragma unroll
        for (int ntp = 0; ntp < 2; ++ntp) acc[mt][ntp] = 0;
#pragma unroll
      for (int ntp = 0; ntp < 2; ++ntp) {
        const int nt = 2 * half + ntp;
        ABu bh, bl;
        bh.u4 = w2fh[ofs0 + nt * 64 + lane];
        bl.u4 = w2fl[ofs0 + nt * 64 + lane];
        acc[0][ntp] = __builtin_amdgcn_mfma_f32_16x16x32_bf16(ah0.s, bh.s, acc[0][ntp], 0, 0, 0);
        acc[0][ntp] = __builtin_amdgcn_mfma_f32_16x16x32_bf16(al0.s, bh.s, acc[0][ntp], 0, 0, 0);
        acc[0][ntp] = __builtin_amdgcn_mfma_f32_16x16x32_bf16(ah0.s, bl.s, acc[0][ntp], 0, 0, 0);
        acc[0][ntp] = __builtin_amdgcn_mfma_f32_16x16x32_bf16(al0.s, bl.s, acc[0][ntp], 0, 0, 0);
        acc[1][ntp] = __builtin_amdgcn_mfma_f32_16x16x32_bf16(ah1.s, bh.s, acc[1][ntp], 0, 0, 0);
        acc[1][ntp] = __builtin_amdgcn_mfma_f32_16x16x32_bf16(al1.s, bh.s, acc[1][ntp], 0, 0, 0);
        acc[1][ntp] = __builtin_amdgcn_mfma_f32_16x16x32_bf16(ah1.s, bl.s, acc[1][ntp], 0, 0, 0);
        acc[1][ntp] = __builtin_amdgcn_mfma_f32_16x16x32_bf16(al1.s, bl.s, acc[1][ntp], 0, 0, 0);
      }
      // C layout: col=lane&15 (=ch mod 16), row=4g+reg; regs (0,1)/(2,3)
      // are voxel pairs of pillars 8mt+2g / 8mt+2g+1.  +b2 here.
#pragma unroll
      for (int ntp = 0; ntp < 2; ++ntp) {
        const float b2v = b2b[16 * (2 * half + ntp) + c16];
#pragma unroll
        for (int mt = 0; mt < 2; ++mt)
#pragma unroll
          for (int rp = 0; rp < 2; ++rp) {
            const int p = 8 * mt + 2 * g + rp;
            float2 v2;
            v2.x = acc[mt][ntp][2 * rp]     + b2v;
            v2.y = acc[mt][ntp][2 * rp + 1] + b2v;
            yb2[p * 34 + 16 * ntp + c16] = v2;
          }
      }
      if ((q >> 1) == half) {           // lanes whose channels are in this half
#pragma unroll
        for (int kk = 0; kk < 8; ++kk) {
          float4 t = yb4[pp * 17 + 8 * (q & 1) + kk];
          y0[2 * kk]     = t.x; y1[2 * kk]     = t.y;
          y0[2 * kk + 1] = t.z; y1[2 * kk + 1] = t.w;
        }
      }
      drain_lds();                      // reads done before next-half writes
    }

    // ---- post-processing: identical to R15 from here on
    const bool has2 = (cnt >= 2);
    const int b1e = has2 ? (b1raw & 31) : 64;
#pragma unroll
    for (int k = 0; k < 16; ++k) y1[k] = has2 ? y1[k] : y0[k];

    // pooled stats + chMLP layer1 partials (thread-local over 16 ch)
    float ha[16] = {0}, hm[16] = {0};
    const float kf = has2 ? 30.0f : 31.0f;     // 32 - nocc
    const float inv32 = 1.0f / 32.0f;
    const float4* c04 = (const float4*)c0b;
    const float4* wc14 = (const float4*)wc1b;
#pragma unroll
    for (int kb = 0; kb < 4; ++kb) {
      float4 cq = c04[q * 4 + kb];
      float c0a[4] = {cq.x, cq.y, cq.z, cq.w};
#pragma unroll
      for (int i = 0; i < 4; ++i) {
        const int k = 4 * kb + i;
        const float c0v = c0a[i];
        const float sumy = y0[k] + (has2 ? y1[k] : 0.0f);
        const float avg = fmaf(c0v, kf, sumy) * inv32;
        const float mxv = fmaxf(fmaxf(y0[k], y1[k]), c0v);
#pragma unroll
        for (int jb = 0; jb < 4; ++jb) {
          float4 w = wc14[(4 * k + q) * 4 + jb];   // k-major: q 2-way, free
          ha[4 * jb]     += avg * w.x; ha[4 * jb + 1] += avg * w.y;
          ha[4 * jb + 2] += avg * w.z; ha[4 * jb + 3] += avg * w.w;
          hm[4 * jb]     += mxv * w.x; hm[4 * jb + 1] += mxv * w.y;
          hm[4 * jb + 2] += mxv * w.z; hm[4 * jb + 3] += mxv * w.w;
        }
      }
    }
    // quad-reduce partials, bias, relu, combine pools
    float gq[16];
    const float4* bc14 = (const float4*)bc1b;
#pragma unroll
    for (int jb = 0; jb < 4; ++jb) {
      float4 bb = bc14[jb];
      float bba[4] = {bb.x, bb.y, bb.z, bb.w};
#pragma unroll
      for (int i = 0; i < 4; ++i) {
        const int j = 4 * jb + i;
        const float sa = qsum4(ha[j]) + bba[i];
        const float sm = qsum4(hm[j]) + bba[i];
        gq[j] = fmaxf(sa, 0.0f) + fmaxf(sm, 0.0f);
      }
    }

    // chMLP layer2 -> attc; bin-column partial reductions
    float attc[16];
    float sc = 0.0f, mc = -3.0e38f;
    float sy0 = 0.0f, my0 = -3.0e38f, sy1 = 0.0f, my1 = -3.0e38f;
    const float4* wc24 = (const float4*)wc2b;
    const float4* bc24 = (const float4*)bc2b;
#pragma unroll
    for (int kb = 0; kb < 4; ++kb) {
      float4 cq = c04[q * 4 + kb];
      float4 bq = bc24[q * 4 + kb];
      float c0a[4] = {cq.x, cq.y, cq.z, cq.w};
      float b2a[4] = {bq.x, bq.y, bq.z, bq.w};
#pragma unroll
      for (int i = 0; i < 4; ++i) {
        const int k = 4 * kb + i;
        float pre = 2.0f * b2a[i];
#pragma unroll
        for (int jb = 0; jb < 4; ++jb) {
          float4 w = wc24[(4 * k + q) * 4 + jb];
          pre += gq[4 * jb] * w.x + gq[4 * jb + 1] * w.y +
                 gq[4 * jb + 2] * w.z + gq[4 * jb + 3] * w.w;
        }
        const float a = sgm(pre);
        attc[k] = a;
        const float pc0 = a * c0a[i], py0 = a * y0[k], py1 = a * y1[k];
        sc += pc0;  mc = fmaxf(mc, pc0);
        sy0 += py0; my0 = fmaxf(my0, py0);
        sy1 += py1; my1 = fmaxf(my1, py1);
      }
    }
    sc = qsum4(sc);   mc = qmax4(mc);
    sy0 = qsum4(sy0); my0 = qmax4(my0);
    sy1 = qsum4(sy1); my1 = qmax4(my1);

    // analytic conv over 32 bins, 8 bins per lane, quad-combined
    const float inv64 = 1.0f / 64.0f;
    const float Mn = sc * inv64, Mx = mc;
    const float dm0 = (sy0 - sc) * inv64, dx0 = my0 - mc;
    const float dm1 = (sy1 - sc) * inv64, dx1 = my1 - mc;
    const float bspr = bsp[0];
    const float2* ws2 = (const float2*)wsmx;
    const float2* wt2 = (const float2*)wtab;
    float maxE = -3.0e38f, minE = 3.0e38f, sv0 = -3.0e38f, sv1 = -3.0e38f;
#pragma unroll
    for (int k = 0; k < 8; ++k) {
      const int b = 8 * q + k;
      float2 ws = ws2[b];
      float acc2 = bspr + Mn * ws.x + Mx * ws.y;
      int k0 = b0 - b + 3;  k0 = ((unsigned)k0 <= 6u) ? k0 : 7;
      int k1 = b1e - b + 3; k1 = ((unsigned)k1 <= 6u) ? k1 : 7;
      float2 w0 = wt2[k0];
      float2 w1v = wt2[k1];
      acc2 += dm0 * w0.x + dx0 * w0.y + dm1 * w1v.x + dx1 * w1v.y;
      const bool o0 = (b == b0), o1 = (b == b1e);
      const bool oc = o0 || o1;
      maxE = fmaxf(maxE, oc ? -3.0e38f : acc2);
      minE = fminf(minE, oc ?  3.0e38f : acc2);
      sv0 = o0 ? acc2 : sv0;
      sv1 = o1 ? acc2 : sv1;
    }
    maxE = qmax4(maxE); minE = qmin4(minE);
    sv0 = qmax4(sv0);   sv1 = qmax4(sv1);
    const float sig0 = sgm(sv0);
    const float sig1 = has2 ? sgm(sv1) : sig0;
    const float sE = sgm(maxE), sI = sgm(minE);

    // epilogue: final max over bins, stores
    if (pg < U) {
      float4* ov = (float4*)(out + (size_t)pg * CO + 16 * q);
#pragma unroll
      for (int kb = 0; kb < 4; ++kb) {
        float4 cq = c04[q * 4 + kb];
        float c0a[4] = {cq.x, cq.y, cq.z, cq.w};
        float rr[4];
#pragma unroll
        for (int i = 0; i < 4; ++i) {
          const int k = 4 * kb + i;
          const float c0v = c0a[i];
          const float sel = (c0v >= 0.0f) ? sE : sI;
          const float m = fmaxf(fmaxf(y0[k] * sig0, y1[k] * sig1), c0v * sel);
          rr[i] = attc[k] * m;
        }
        float4 r; r.x = rr[0]; r.y = rr[1]; r.z = rr[2]; r.w = rr[3];
        ov[kb] = r;
      }
      if (q == 0) out[(size_t)U * CO + pg] = has2 ? 1.0f : 0.0f;
    }

    // ---- next trip's vbuf fill must have landed before reuse
    drain_vm();
  }
}

extern "C" void kernel_launch(void* const* d_in, const int* in_sizes, int n_in,
                              void* d_out, int out_size, void* d_ws, size_t ws_size,
                              hipStream_t stream) {
  const float* vf      = (const float*)d_in[0];
  const int*   vcoord  = (const int*)d_in[1];
  // d_in[2] = unq_coords (unused: identity)
  const int*   unq_inv = (const int*)d_in[3];
  const int*   unq_cnt = (const int*)d_in[4];
  const float* W1  = (const float*)d_in[5];
  const float* b1  = (const float*)d_in[6];
  const float* W2  = (const float*)d_in[7];
  const float* b2  = (const float*)d_in[8];
  const float* Wc1 = (const float*)d_in[9];
  const float* bc1 = (const float*)d_in[10];
  const float* Wc2 = (const float*)d_in[11];
  const float* bc2 = (const float*)d_in[12];
  const float* Wsp = (const float*)d_in[13];
  const float* bsp = (const float*)d_in[14];

  const int N = in_sizes[3];   // voxels
  const int U = in_sizes[4];   // pillars

  float* pvox = (float*)d_ws;  // 2U records x 32B (6.4 MB @ U=100k)

  pack_kernel<<<(N + 255) / 256, 256, 0, stream>>>(vf, vcoord, unq_inv, pvox, N);

  // resident blocks/CU from compiled resources (host-side query, capture-safe)
  static int blocksPerCU = 0;
  if (blocksPerCU == 0) {
    hipFuncAttributes a{};
    blocksPerCU = 4;
    if (hipFuncGetAttributes(&a, (const void*)cbam_kernel) == hipSuccess) {
      int byV = (a.numRegs > 0) ? (512 / a.numRegs) : 4;           // waves/SIMD
      int byL = (a.sharedSizeBytes > 0)
                    ? (int)(163840 / (int)a.sharedSizeBytes) : 4;  // blocks/CU
      int m = byV < byL ? byV : byL;
      if (m < 1) m = 1;
      if (m > 8) m = 8;
      blocksPerCU = m;
    }
  }

  const int ngroups = (U + 15) / 16;      // 16 pillars per wave-trip
  int blocks = 256 * blocksPerCU;         // exactly-resident persistent grid
  const int maxBlocks = (ngroups + 3) / 4;
  if (blocks > maxBlocks) blocks = maxBlocks;
  const int totalWaves = blocks * 4;
  cbam_kernel<<<blocks, 256, 0, stream>>>(
      pvox, unq_cnt, W1, b1, W2, b2, Wc1, bc1, Wc2, bc2, Wsp, bsp,
      (float*)d_out, U, ngroups, totalWaves);
}